// Round 4
// baseline (199.869 us; speedup 1.0000x reference)
//
#include <hip/hip_runtime.h>
#include <hip/hip_bf16.h>

typedef __attribute__((ext_vector_type(4))) float f32x4;
typedef __attribute__((ext_vector_type(16))) float f32x16;
typedef __attribute__((ext_vector_type(8))) short short8;

static constexpr int Ssz = 2048;
static constexpr int Dsz = 1024;

__device__ __forceinline__ unsigned short f2bf(float f){
  union { float f; unsigned u; } c; c.f = f;
  unsigned r = c.u + 0x7fffu + ((c.u >> 16) & 1u);
  return (unsigned short)(r >> 16);
}

__device__ __forceinline__ void gl2lds16(const void* g, void* l){
  __builtin_amdgcn_global_load_lds(
    (const __attribute__((address_space(1))) unsigned int*)g,
    (__attribute__((address_space(3))) unsigned int*)l, 16, 0, 0);
}

__device__ __forceinline__ unsigned cvtpk(float lo, float hi){
  unsigned r;
  asm("v_cvt_pk_bf16_f32 %0, %1, %2" : "=v"(r) : "v"(lo), "v"(hi));
  return r;
}

__device__ __forceinline__ void permswap(unsigned &a, unsigned &b){
  asm volatile("v_permlane32_swap_b32 %0, %1" : "+v"(a), "+v"(b));
}

__device__ __forceinline__ float xmax64(float x){
  float a = x, b;
  asm volatile("v_mov_b32 %0, %1" : "=v"(b) : "v"(a));
  asm volatile("v_permlane32_swap_b32 %0, %1" : "+v"(a), "+v"(b));
  return fmaxf(a, b);
}
__device__ __forceinline__ float xsum64(float x){
  float a = x, b;
  asm volatile("v_mov_b32 %0, %1" : "=v"(b) : "v"(a));
  asm volatile("v_permlane32_swap_b32 %0, %1" : "+v"(a), "+v"(b));
  return a + b;
}

// ---------------- fp32 -> bf16 elementwise (8/thread) ----------------
__global__ void cvt_kernel(const float* __restrict__ in, unsigned short* __restrict__ out, int n){
  int i = (blockIdx.x * 256 + threadIdx.x) * 8;
  if (i >= n) return;
  float4 a = *(const float4*)(in + i);
  float4 b = *(const float4*)(in + i + 4);
  short8 o;
  o[0]=(short)f2bf(a.x); o[1]=(short)f2bf(a.y); o[2]=(short)f2bf(a.z); o[3]=(short)f2bf(a.w);
  o[4]=(short)f2bf(b.x); o[5]=(short)f2bf(b.y); o[6]=(short)f2bf(b.z); o[7]=(short)f2bf(b.w);
  *(short8*)(out + i) = o;
}

// ---------------- fp32 [R][C] -> bf16 [C][R] transpose ----------------
__global__ void transpose_kernel(const float* __restrict__ in, unsigned short* __restrict__ out,
                                 int R, int C){
  __shared__ float tile[32][33];
  int c0 = blockIdx.x * 32, r0 = blockIdx.y * 32;
  int tx = threadIdx.x, ty = threadIdx.y;
  #pragma unroll
  for (int k = 0; k < 4; ++k)
    tile[ty + 8*k][tx] = in[(size_t)(r0 + ty + 8*k) * C + c0 + tx];
  __syncthreads();
  #pragma unroll
  for (int k = 0; k < 4; ++k)
    out[(size_t)(c0 + ty + 8*k) * R + r0 + tx] = f2bf(tile[tx][ty + 8*k]);
}

// ============ QKV GEMM: 256x256 tile, BK=64, 8-phase schedule (T2+T3+T4+T5) ============
// M=8192, N=3072, K=1024. grid 384 = 32m x 12n, 512 threads = 8 waves (2M x 4N).
// Stripes per K-tile (16KB = 2 gl2lds/thread): 0=B-lo(nh0), 1=A-lo(mh0), 2=A-hi(mh1), 3=B-hi(nh1).
// Quadrants per K-tile: q0=(0,0) q1=(1,0) q2=(1,1) q3=(0,1). Stage lead = 5 stripes.
// vmcnt(6) at ends of q0,q1,q3 (= 3 stripes x 2 loads in flight); none at q2.
__global__ __launch_bounds__(512, 2)
void gemm_qkv(const unsigned short* __restrict__ A, const unsigned short* __restrict__ Bt,
              const float* __restrict__ bias,
              unsigned short* __restrict__ Qp, unsigned short* __restrict__ Kp,
              unsigned short* __restrict__ Vtp)
{
  constexpr int K = 1024, NT = 16;
  __shared__ unsigned short ldsA[2][256 * 64];
  __shared__ unsigned short ldsB[2][256 * 64];
  const int tid = threadIdx.x;
  const int wid = tid >> 6, lane = tid & 63;
  const int lr = lane & 15, lg = lane >> 4;
  const int wm = wid >> 2, wn = wid & 3;

  // XCD-aware swizzle (384 % 8 == 0)
  int bid = blockIdx.x;
  int swz = (bid & 7) * 48 + (bid >> 3);
  const int m0 = (swz / 12) * 256, n0 = (swz % 12) * 256;

  const f32x4 vzero = {0.f, 0.f, 0.f, 0.f};
  f32x4 acc[8][4];
  #pragma unroll
  for (int i = 0; i < 8; ++i)
    #pragma unroll
    for (int j = 0; j < 4; ++j) acc[i][j] = vzero;

  auto stage = [&](int sigma){
    if (sigma >= 4 * NT) return;
    const int ts = sigma >> 2, ss = sigma & 3;
    const int buf = ts & 1;
    #pragma unroll
    for (int call = 0; call < 2; ++call){
      int c = call * 512 + tid;
      int rw = c >> 3, cc = c & 7;
      if (ss == 0 || ss == 3){
        int row = ((rw >> 5) << 6) + (rw & 31) + (ss == 3 ? 32 : 0);
        int sc = cc ^ (row & 7);
        gl2lds16(Bt + (size_t)(n0 + row) * K + ts * 64 + sc * 8,
                 &ldsB[buf][row * 64 + cc * 8]);
      } else {
        int row = ((rw >> 6) << 7) + (rw & 63) + (ss == 2 ? 64 : 0);
        int sc = cc ^ (row & 7);
        gl2lds16(A + (size_t)(m0 + row) * K + ts * 64 + sc * 8,
                 &ldsA[buf][row * 64 + cc * 8]);
      }
    }
  };

  short8 af[4][2], bf2[2][2];

  // prologue: stripes 0..4 (tile0 complete + tile1 B-lo), then verify tile0 {B-lo,A-lo}
  stage(0); stage(1); stage(2); stage(3); stage(4);
  asm volatile("s_waitcnt vmcnt(6)" ::: "memory");
  __builtin_amdgcn_sched_barrier(0);
  __builtin_amdgcn_s_barrier();

  #pragma unroll 1
  for (int t = 0; t < NT; ++t){
    const char* baA = (const char*)&ldsA[t & 1][0];
    const char* baB = (const char*)&ldsB[t & 1][0];

    // ---- phase q0: quadrant (mh=0, nh=0); read A-lo + B-lo ----
    #pragma unroll
    for (int ii = 0; ii < 4; ++ii)
      #pragma unroll
      for (int kk = 0; kk < 2; ++kk){
        int row = wm * 128 + ii * 16 + lr;
        int off = (row * 128 + lg * 16 + kk * 64) ^ ((row & 7) << 4);
        af[ii][kk] = *(const short8*)(baA + off);
      }
    #pragma unroll
    for (int jj = 0; jj < 2; ++jj)
      #pragma unroll
      for (int kk = 0; kk < 2; ++kk){
        int row = wn * 64 + jj * 16 + lr;
        int off = (row * 128 + lg * 16 + kk * 64) ^ ((row & 7) << 4);
        bf2[jj][kk] = *(const short8*)(baB + off);
      }
    stage(4 * t + 5);
    __builtin_amdgcn_s_barrier();
    asm volatile("s_waitcnt lgkmcnt(0)" ::: "memory");
    __builtin_amdgcn_sched_barrier(0);
    __builtin_amdgcn_s_setprio(1);
    #pragma unroll
    for (int ii = 0; ii < 4; ++ii)
      #pragma unroll
      for (int jj = 0; jj < 2; ++jj)
        #pragma unroll
        for (int kk = 0; kk < 2; ++kk)
          acc[ii][jj] = __builtin_amdgcn_mfma_f32_16x16x32_bf16(af[ii][kk], bf2[jj][kk], acc[ii][jj], 0, 0, 0);
    __builtin_amdgcn_s_setprio(0);
    asm volatile("s_waitcnt vmcnt(6)" ::: "memory");
    __builtin_amdgcn_sched_barrier(0);
    __builtin_amdgcn_s_barrier();

    // ---- phase q1: quadrant (mh=1, nh=0); read A-hi, reuse B ----
    #pragma unroll
    for (int ii = 0; ii < 4; ++ii)
      #pragma unroll
      for (int kk = 0; kk < 2; ++kk){
        int row = wm * 128 + 64 + ii * 16 + lr;
        int off = (row * 128 + lg * 16 + kk * 64) ^ ((row & 7) << 4);
        af[ii][kk] = *(const short8*)(baA + off);
      }
    stage(4 * t + 6);
    __builtin_amdgcn_s_barrier();
    asm volatile("s_waitcnt lgkmcnt(0)" ::: "memory");
    __builtin_amdgcn_sched_barrier(0);
    __builtin_amdgcn_s_setprio(1);
    #pragma unroll
    for (int ii = 0; ii < 4; ++ii)
      #pragma unroll
      for (int jj = 0; jj < 2; ++jj)
        #pragma unroll
        for (int kk = 0; kk < 2; ++kk)
          acc[4 + ii][jj] = __builtin_amdgcn_mfma_f32_16x16x32_bf16(af[ii][kk], bf2[jj][kk], acc[4 + ii][jj], 0, 0, 0);
    __builtin_amdgcn_s_setprio(0);
    asm volatile("s_waitcnt vmcnt(6)" ::: "memory");
    __builtin_amdgcn_sched_barrier(0);
    __builtin_amdgcn_s_barrier();

    // ---- phase q2: quadrant (mh=1, nh=1); read B-hi, reuse A ----
    #pragma unroll
    for (int jj = 0; jj < 2; ++jj)
      #pragma unroll
      for (int kk = 0; kk < 2; ++kk){
        int row = wn * 64 + 32 + jj * 16 + lr;
        int off = (row * 128 + lg * 16 + kk * 64) ^ ((row & 7) << 4);
        bf2[jj][kk] = *(const short8*)(baB + off);
      }
    stage(4 * t + 7);
    __builtin_amdgcn_s_barrier();
    asm volatile("s_waitcnt lgkmcnt(0)" ::: "memory");
    __builtin_amdgcn_sched_barrier(0);
    __builtin_amdgcn_s_setprio(1);
    #pragma unroll
    for (int ii = 0; ii < 4; ++ii)
      #pragma unroll
      for (int jj = 0; jj < 2; ++jj)
        #pragma unroll
        for (int kk = 0; kk < 2; ++kk)
          acc[4 + ii][2 + jj] = __builtin_amdgcn_mfma_f32_16x16x32_bf16(af[ii][kk], bf2[jj][kk], acc[4 + ii][2 + jj], 0, 0, 0);
    __builtin_amdgcn_s_setprio(0);
    __builtin_amdgcn_s_barrier();

    // ---- phase q3: quadrant (mh=0, nh=1); re-read A-lo, reuse B-hi ----
    #pragma unroll
    for (int ii = 0; ii < 4; ++ii)
      #pragma unroll
      for (int kk = 0; kk < 2; ++kk){
        int row = wm * 128 + ii * 16 + lr;
        int off = (row * 128 + lg * 16 + kk * 64) ^ ((row & 7) << 4);
        af[ii][kk] = *(const short8*)(baA + off);
      }
    stage(4 * t + 8);
    __builtin_amdgcn_s_barrier();
    asm volatile("s_waitcnt lgkmcnt(0)" ::: "memory");
    __builtin_amdgcn_sched_barrier(0);
    __builtin_amdgcn_s_setprio(1);
    #pragma unroll
    for (int ii = 0; ii < 4; ++ii)
      #pragma unroll
      for (int jj = 0; jj < 2; ++jj)
        #pragma unroll
        for (int kk = 0; kk < 2; ++kk)
          acc[ii][2 + jj] = __builtin_amdgcn_mfma_f32_16x16x32_bf16(af[ii][kk], bf2[jj][kk], acc[ii][2 + jj], 0, 0, 0);
    __builtin_amdgcn_s_setprio(0);
    asm volatile("s_waitcnt vmcnt(6)" ::: "memory");
    __builtin_amdgcn_sched_barrier(0);
    __builtin_amdgcn_s_barrier();
  }

  asm volatile("s_waitcnt vmcnt(0)" ::: "memory");

  // epilogue: bias + scatter to Q (exp2-domain prescale), K, V^T
  const float qscale = 0.125f * 1.4426950408889634f;
  #pragma unroll
  for (int i = 0; i < 8; ++i)
    #pragma unroll
    for (int j = 0; j < 4; ++j)
      #pragma unroll
      for (int r = 0; r < 4; ++r){
        int gm = m0 + wm * 128 + i * 16 + lg * 4 + r;
        int gn = n0 + wn * 64 + j * 16 + lr;
        float v = acc[i][j][r] + bias[gn];
        int which = gn >> 10;
        int h = (gn >> 6) & 15;
        int hd = gn & 63;
        int b = gm >> 11;
        int s = gm & 2047;
        size_t bh = (size_t)(b * 16 + h);
        if (which == 0)      Qp[(bh * Ssz + s) * 64 + hd] = f2bf(v * qscale);
        else if (which == 1) Kp[(bh * Ssz + s) * 64 + hd] = f2bf(v);
        else                 Vtp[(bh * 64 + hd) * Ssz + s] = f2bf(v);
      }
}

// ---------------- bf16 GEMM (out-proj): C[M][N] = A[M][K] * Bt[N][K]^T + bias ----------------
#define BM 128
#define BN 128
#define BKg 64

__global__ __launch_bounds__(256, 2)
void gemm_bt(const unsigned short* __restrict__ A, const unsigned short* __restrict__ Bt,
             int M, int N, int K,
             const float* __restrict__ bias, float* __restrict__ Out)
{
  __shared__ unsigned short ldsA[BM * BKg];
  __shared__ unsigned short ldsB[BN * BKg];
  const int tid = threadIdx.x;
  const int wid = tid >> 6;
  const int lane = tid & 63;
  const int lr = lane & 15, lg = lane >> 4;
  const int wr = wid >> 1, wc = wid & 1;
  const int m0 = blockIdx.y * BM, n0 = blockIdx.x * BN;

  const f32x4 vzero = {0.f, 0.f, 0.f, 0.f};
  f32x4 acc[4][4];
  #pragma unroll
  for (int i = 0; i < 4; ++i)
    #pragma unroll
    for (int j = 0; j < 4; ++j) acc[i][j] = vzero;

  for (int k0 = 0; k0 < K; k0 += BKg){
    __syncthreads();
    #pragma unroll
    for (int it = 0; it < 4; ++it){
      int c = it * 256 + tid;
      int row = c >> 3;
      int sc = (c & 7) ^ (row & 7);
      gl2lds16(A  + (size_t)(m0 + row) * K + k0 + sc * 8,
               (char*)ldsA + (it * 256 + wid * 64) * 16);
      gl2lds16(Bt + (size_t)(n0 + row) * K + k0 + sc * 8,
               (char*)ldsB + (it * 256 + wid * 64) * 16);
    }
    __syncthreads();
    #pragma unroll
    for (int kc = 0; kc < 2; ++kc){
      short8 af[4], bfr[4];
      #pragma unroll
      for (int i = 0; i < 4; ++i){
        int row = wr * 64 + i * 16 + lr;
        int off = row * 128 + lg * 16 + kc * 64;
        off ^= (row & 7) << 4;
        af[i] = *(const short8*)((const char*)ldsA + off);
      }
      #pragma unroll
      for (int j = 0; j < 4; ++j){
        int row = wc * 64 + j * 16 + lr;
        int off = row * 128 + lg * 16 + kc * 64;
        off ^= (row & 7) << 4;
        bfr[j] = *(const short8*)((const char*)ldsB + off);
      }
      #pragma unroll
      for (int i = 0; i < 4; ++i)
        #pragma unroll
        for (int j = 0; j < 4; ++j)
          acc[i][j] = __builtin_amdgcn_mfma_f32_16x16x32_bf16(af[i], bfr[j], acc[i][j], 0, 0, 0);
    }
  }

  #pragma unroll
  for (int i = 0; i < 4; ++i)
    #pragma unroll
    for (int j = 0; j < 4; ++j)
      #pragma unroll
      for (int r = 0; r < 4; ++r){
        int gm = m0 + wr * 64 + i * 16 + lg * 4 + r;
        int gn = n0 + wc * 64 + j * 16 + lr;
        Out[(size_t)gm * N + gn] = acc[i][j][r] + bias[gn];
      }
}

// ---------------- causal flash attention, swapped-QK 32x32, balanced ----------------
__global__ __launch_bounds__(256, 2)
void attn_kernel(const unsigned short* __restrict__ Qp, const unsigned short* __restrict__ Kp,
                 const unsigned short* __restrict__ Vtp, unsigned short* __restrict__ Att)
{
  __shared__ unsigned short ldsK[2][4096];
  __shared__ unsigned short ldsV[2][4096];
  const int tid = threadIdx.x;
  const int wid = tid >> 6;
  const int lane = tid & 63;
  const int lq = lane & 31;
  const int hi = lane >> 5;
  const int bh = blockIdx.y;
  const int b = bh >> 4, hh = bh & 15;

  #pragma unroll 1
  for (int job = 0; job < 2; ++job){
    const int qt = job ? (15 - (int)blockIdx.x) : (int)blockIdx.x;
    const int q0w = qt * 128 + wid * 32;
    const int qa = q0w + lq;
    const int nt = 2 * qt + 2;

    short8 qf[4];
    {
      const unsigned short* Qb = Qp + ((size_t)bh * Ssz + q0w + lq) * 64 + hi * 8;
      #pragma unroll
      for (int ks = 0; ks < 4; ++ks) qf[ks] = *(const short8*)(Qb + ks * 16);
    }

    f32x16 Ot[2];
    #pragma unroll
    for (int d = 0; d < 2; ++d)
      #pragma unroll
      for (int r = 0; r < 16; ++r) Ot[d][r] = 0.f;
    float mrun = -3e38f, lsum = 0.f;

    #pragma unroll
    for (int it = 0; it < 2; ++it){
      int c = it * 256 + tid;
      int row = c >> 3, sc = (c & 7) ^ (row & 7);
      gl2lds16(Kp  + ((size_t)bh * Ssz + row) * 64 + sc * 8,
               (char*)&ldsK[0][0] + (it * 256 + wid * 64) * 16);
      gl2lds16(Vtp + ((size_t)bh * 64 + row) * Ssz + sc * 8,
               (char*)&ldsV[0][0] + (it * 256 + wid * 64) * 16);
    }
    __syncthreads();

    for (int kt = 0; kt < nt; ++kt){
      const int cur = kt & 1;
      if (kt + 1 < nt){
        const int nxt = cur ^ 1;
        #pragma unroll
        for (int it = 0; it < 2; ++it){
          int c = it * 256 + tid;
          int row = c >> 3, sc = (c & 7) ^ (row & 7);
          gl2lds16(Kp  + ((size_t)bh * Ssz + (kt + 1) * 64 + row) * 64 + sc * 8,
                   (char*)&ldsK[nxt][0] + (it * 256 + wid * 64) * 16);
          gl2lds16(Vtp + ((size_t)bh * 64 + row) * Ssz + (kt + 1) * 64 + sc * 8,
                   (char*)&ldsV[nxt][0] + (it * 256 + wid * 64) * 16);
        }
      }

      if (kt * 64 <= q0w + 31){
        const char* Kb = (const char*)&ldsK[cur][0];
        const char* Vb = (const char*)&ldsV[cur][0];

        f32x16 S[2];
        #pragma unroll
        for (int kb = 0; kb < 2; ++kb)
          #pragma unroll
          for (int r = 0; r < 16; ++r) S[kb][r] = 0.f;
        #pragma unroll
        for (int ks = 0; ks < 4; ++ks){
          int col = 32 * ks + 16 * hi;
          int r0 = lq, r1 = 32 + lq;
          short8 k0 = *(const short8*)(Kb + ((r0 * 128 + col) ^ ((r0 & 7) << 4)));
          short8 k1 = *(const short8*)(Kb + ((r1 * 128 + col) ^ ((r1 & 7) << 4)));
          S[0] = __builtin_amdgcn_mfma_f32_32x32x16_bf16(k0, qf[ks], S[0], 0, 0, 0);
          S[1] = __builtin_amdgcn_mfma_f32_32x32x16_bf16(k1, qf[ks], S[1], 0, 0, 0);
        }

        if (kt * 64 + 63 > q0w){
          #pragma unroll
          for (int r = 0; r < 16; ++r){
            int keyb = kt * 64 + (r & 3) + ((r >> 2) << 3) + 4 * hi;
            if (keyb > qa)      S[0][r] = -3e38f;
            if (keyb + 32 > qa) S[1][r] = -3e38f;
          }
        }

        float t16[16];
        #pragma unroll
        for (int r = 0; r < 16; ++r) t16[r] = fmaxf(S[0][r], S[1][r]);
        float t8[8];
        #pragma unroll
        for (int r = 0; r < 8; ++r) t8[r] = fmaxf(t16[r], t16[r + 8]);
        float t4[4];
        #pragma unroll
        for (int r = 0; r < 4; ++r) t4[r] = fmaxf(t8[r], t8[r + 4]);
        float pmax = fmaxf(fmaxf(t4[0], t4[1]), fmaxf(t4[2], t4[3]));
        pmax = xmax64(pmax);

        if (!__all(pmax - mrun <= 8.0f)){
          float mn = fmaxf(mrun, pmax);
          float scl = __builtin_amdgcn_exp2f(mrun - mn);
          mrun = mn;
          lsum *= scl;
          #pragma unroll
          for (int d = 0; d < 2; ++d)
            #pragma unroll
            for (int r = 0; r < 16; ++r) Ot[d][r] *= scl;
        }

        #pragma unroll
        for (int kb = 0; kb < 2; ++kb)
          #pragma unroll
          for (int r = 0; r < 16; ++r)
            S[kb][r] = __builtin_amdgcn_exp2f(S[kb][r] - mrun);

        #pragma unroll
        for (int r = 0; r < 16; ++r) t16[r] = S[0][r] + S[1][r];
        #pragma unroll
        for (int r = 0; r < 8; ++r) t8[r] = t16[r] + t16[r + 8];
        #pragma unroll
        for (int r = 0; r < 4; ++r) t4[r] = t8[r] + t8[r + 4];
        float psum = (t4[0] + t4[1]) + (t4[2] + t4[3]);
        psum = xsum64(psum);
        lsum += psum;

        #pragma unroll
        for (int s = 0; s < 4; ++s){
          const int sb = s >> 1, s1 = s & 1;
          unsigned u0 = cvtpk(S[sb][8 * s1 + 0], S[sb][8 * s1 + 1]);
          unsigned u1 = cvtpk(S[sb][8 * s1 + 2], S[sb][8 * s1 + 3]);
          unsigned u2 = cvtpk(S[sb][8 * s1 + 4], S[sb][8 * s1 + 5]);
          unsigned u3 = cvtpk(S[sb][8 * s1 + 6], S[sb][8 * s1 + 7]);
          permswap(u0, u2);
          permswap(u1, u3);
          union { unsigned u[4]; short8 s8; } pb;
          pb.u[0] = u0; pb.u[1] = u1; pb.u[2] = u2; pb.u[3] = u3;

          int col = 32 * s + 16 * hi;
          int r0 = lq, r1 = 32 + lq;
          short8 v0 = *(const short8*)(Vb + ((r0 * 128 + col) ^ ((r0 & 7) << 4)));
          short8 v1 = *(const short8*)(Vb + ((r1 * 128 + col) ^ ((r1 & 7) << 4)));
          Ot[0] = __builtin_amdgcn_mfma_f32_32x32x16_bf16(v0, pb.s8, Ot[0], 0, 0, 0);
          Ot[1] = __builtin_amdgcn_mfma_f32_32x32x16_bf16(v1, pb.s8, Ot[1], 0, 0, 0);
        }
      }
      __syncthreads();
    }

    float inv = 1.0f / lsum;
    unsigned short* ep = &ldsK[0][0] + wid * 2048;
    #pragma unroll
    for (int d = 0; d < 2; ++d)
      #pragma unroll
      for (int g = 0; g < 4; ++g)
        #pragma unroll
        for (int cp = 0; cp < 2; ++cp){
          int r = g * 4 + cp * 2;
          unsigned w = cvtpk(Ot[d][r] * inv, Ot[d][r + 1] * inv);
          int dd = d * 32 + g * 8 + 4 * hi + cp * 2;
          int byte = lq * 128 + ((dd * 2) ^ ((lq & 7) << 4));
          *(unsigned*)((char*)ep + byte) = w;
        }
    __syncthreads();
    #pragma unroll
    for (int i = 0; i < 4; ++i){
      int qr = i * 8 + (lane >> 3);
      int cc = lane & 7;
      int byte = qr * 128 + ((cc * 16) ^ ((qr & 7) << 4));
      short8 vv = *(const short8*)((const char*)ep + byte);
      *(short8*)(Att + ((size_t)(b * Ssz + q0w + qr)) * Dsz + hh * 64 + cc * 8) = vv;
    }
    __syncthreads();
  }
}

extern "C" void kernel_launch(void* const* d_in, const int* in_sizes, int n_in,
                              void* d_out, int out_size, void* d_ws, size_t ws_size,
                              hipStream_t stream) {
  const float* x    = (const float*)d_in[0];
  const float* Wqkv = (const float*)d_in[1];
  const float* bqkv = (const float*)d_in[2];
  const float* Wout = (const float*)d_in[3];
  const float* bout = (const float*)d_in[4];
  float* out = (float*)d_out;

  unsigned short* xb    = (unsigned short*)d_ws;                 // 8192*1024
  unsigned short* wqkvT = xb    + (size_t)8192 * 1024;           // 3072*1024
  unsigned short* woutT = wqkvT + (size_t)3072 * 1024;           // 1024*1024
  unsigned short* Qb    = woutT + (size_t)1024 * 1024;           // [B,H,S,HD]
  unsigned short* Kb    = Qb    + (size_t)8388608;
  unsigned short* Vtb   = Kb    + (size_t)8388608;
  unsigned short* Attb  = Vtb   + (size_t)8388608;

  cvt_kernel<<<4096, 256, 0, stream>>>(x, xb, 8388608);
  transpose_kernel<<<dim3(96, 32), dim3(32, 8), 0, stream>>>(Wqkv, wqkvT, 1024, 3072);
  transpose_kernel<<<dim3(32, 32), dim3(32, 8), 0, stream>>>(Wout, woutT, 1024, 1024);
  gemm_qkv<<<384, 512, 0, stream>>>(xb, wqkvT, bqkv, Qb, Kb, Vtb);
  attn_kernel<<<dim3(8, 64), 256, 0, stream>>>(Qb, Kb, Vtb, Attb);
  gemm_bt<<<dim3(8, 64), 256, 0, stream>>>(Attb, woutT, 8192, 1024, 1024, bout, out);
}